// Round 3
// baseline (486.443 us; speedup 1.0000x reference)
//
#include <hip/hip_runtime.h>
#include <math.h>

#define CC   16
#define HH   256
#define WW   256
#define HIDN 128
#define PDIM 144     // C*K*K
#define PH   136     // hT pitch (halfs)
#define OPITCH 146   // o LDS pitch (halfs) -> 292B rows, dword stride 73 = 9 mod 32 (bank-spread)

typedef _Float16 half8 __attribute__((ext_vector_type(8)));
typedef _Float16 half4 __attribute__((ext_vector_type(4)));
typedef _Float16 half2v __attribute__((ext_vector_type(2)));
typedef float    f32x4 __attribute__((ext_vector_type(4)));

#define MFMA16(a, b, c) __builtin_amdgcn_mfma_f32_16x16x32_f16((a), (b), (c), 0, 0, 0)

// ---------------- ws layout (new path) ----------------
// og3[b][a][i][c][xo] fp16 : x-folded partial rows (ypad = 2a+i)
#define OG3_BYTES  ((size_t)32 * 128 * 3 * 16 * 256 * 2)   // 100,663,296
#define XH_OFF     OG3_BYTES
#define XH_BYTES   ((size_t)32 * 256 * 256 * 16 * 2)       // 67,108,864
#define W1T3_OFF   (XH_OFF + XH_BYTES)
#define W1T3_BYTES ((size_t)128 * 144 * 2)
#define W2T3_OFF   (W1T3_OFF + W1T3_BYTES)
#define W2T3_BYTES ((size_t)144 * 128 * 2)
#define WS_NEEDED3 (W2T3_OFF + W2T3_BYTES)                 // ~160.1 MiB

// ---------------- ws layout (round-2 fallback) ----------------
#define K1PAD 160
#define PITCH_P 168
#define PITCH_H 136
#define O_BYTES   ((size_t)524288 * 144 * 2)
#define W1T_OFF   O_BYTES
#define W1T_BYTES ((size_t)128 * K1PAD * 2)
#define W2T_OFF   (W1T_OFF + W1T_BYTES)
#define W2T_BYTES ((size_t)144 * 128 * 2)
#define WS_NEEDED (W2T_OFF + W2T_BYTES)

// ===========================================================================
// NEW PATH
// ===========================================================================

// x (B,C,H,W) fp32 -> xh (B,H,W,C) fp16. One block per (b,y) row.
__global__ __launch_bounds__(256) void transpose_kernel(
    const float* __restrict__ x, _Float16* __restrict__ xh)
{
    const int xcol = threadIdx.x;
    const int y    = blockIdx.x & 255;
    const int b    = blockIdx.x >> 8;
    const float* xb = x + (size_t)b * CC * HH * WW + (size_t)y * WW + xcol;
    half8 w0, w1;
    #pragma unroll
    for (int c = 0; c < 8; ++c) w0[c] = (_Float16)xb[(size_t)c * (HH * WW)];
    #pragma unroll
    for (int c = 0; c < 8; ++c) w1[c] = (_Float16)xb[(size_t)(c + 8) * (HH * WW)];
    _Float16* dst = xh + (((size_t)b * 65536 + (size_t)y * 256 + xcol) << 4);
    *(half8*)(dst)     = w0;
    *(half8*)(dst + 8) = w1;
}

// W1T[n][k'] with k' = tap*16 + c  (tap = i*3+j), maps to orig p = c*9 + tap.
// W2T[nn][k] with nn = tap*16 + c, maps to orig col = c*9 + tap.
__global__ __launch_bounds__(256) void prep3_kernel(
    const float* __restrict__ W1, const float* __restrict__ W2,
    _Float16* __restrict__ W1T, _Float16* __restrict__ W2T)
{
    const int idx = blockIdx.x * 256 + threadIdx.x;
    if (idx < 128 * 144) {
        const int n = idx / 144;
        const int k = idx - n * 144;
        const int c = k & 15, tap = k >> 4;
        W1T[idx] = (_Float16)W1[(c * 9 + tap) * HIDN + n];
    }
    if (idx < 144 * 128) {
        const int nn = idx >> 7, k = idx & 127;
        const int c = nn & 15, tap = nn >> 4;
        W2T[idx] = (_Float16)W2[k * PDIM + c * 9 + tap];
    }
}

// One block = one patch row a (128 patches). Stage xh -> pT (vector),
// MFMA MLP, fold along x in LDS, write og3 coalesced.
__global__ __launch_bounds__(256) void mlp3_kernel(
    const _Float16* __restrict__ xh,
    const _Float16* __restrict__ W1T, const float* __restrict__ b1,
    const _Float16* __restrict__ W2T, const float* __restrict__ b2,
    _Float16* __restrict__ og3)
{
    __shared__ __align__(16) char smem[37376 + 34816];   // 72,192 B -> 2 blocks/CU
    _Float16* pT = (_Float16*)smem;            // [128][144] halfs (pitch 288B)
    _Float16* oL = (_Float16*)smem;            // [128][OPITCH] overlays pT after GEMM1
    _Float16* hT = (_Float16*)(smem + 37376);  // [128][PH]

    const int tid = threadIdx.x;
    const int a   = blockIdx.x & 127;
    const int b   = blockIdx.x >> 7;

    // ---- stage: 2304 16B-chunks; chunk ch -> pT half-index ch*8 (contiguous)
    const _Float16* xhb = xh + ((size_t)b << 20);   // 65536*16 halfs per batch
    #pragma unroll
    for (int it = 0; it < 9; ++it) {
        const int ch   = tid + (it << 8);
        const int bcol = ch / 18;
        const int rem  = ch - bcol * 18;
        const int tap  = rem >> 1, hf = rem & 1;
        const int i    = (tap * 11) >> 5;           // tap/3
        const int j    = tap - i * 3;
        int y  = 2 * a + i - 1;    if (y  < 0) y  = 1;   // reflect pad
        int xc = 2 * bcol + j - 1; if (xc < 0) xc = 1;
        const half8 v = *(const half8*)(xhb + ((((size_t)y << 8) + xc) << 4) + (hf << 3));
        *(half8*)(pT + ((size_t)ch << 3)) = v;
    }
    __syncthreads();

    const int wid = tid >> 6, lane = tid & 63, l15 = lane & 15, quad = lane >> 4;

    // ---- GEMM1: h = relu(patches @ W1 + b1). M=128,N=128,K=144 (4x32 + 16 tail)
    {
        half8 bf[2][4], bt[2];
        float bias1[2];
        #pragma unroll
        for (int n = 0; n < 2; ++n) {
            const int nt = wid * 2 + n;
            const _Float16* wr = W1T + (nt * 16 + l15) * 144;
            #pragma unroll
            for (int ks = 0; ks < 4; ++ks) bf[n][ks] = *(const half8*)(wr + quad * 8 + ks * 32);
            const half4 t4 = *(const half4*)(wr + 128 + quad * 4);
            half8 z = {0, 0, 0, 0, 0, 0, 0, 0};
            z[0] = t4[0]; z[1] = t4[1]; z[2] = t4[2]; z[3] = t4[3];
            bt[n] = z;
            bias1[n] = b1[nt * 16 + l15];
        }
        for (int mt = 0; mt < 8; ++mt) {
            f32x4 acc0 = {0.f, 0.f, 0.f, 0.f};
            f32x4 acc1 = {0.f, 0.f, 0.f, 0.f};
            const _Float16* ar = pT + (mt * 16 + l15) * 144;
            #pragma unroll
            for (int ks = 0; ks < 4; ++ks) {
                const half8 af = *(const half8*)(ar + quad * 8 + ks * 32);
                acc0 = MFMA16(af, bf[0][ks], acc0);
                acc1 = MFMA16(af, bf[1][ks], acc1);
            }
            const half4 a4 = *(const half4*)(ar + 128 + quad * 4);
            half8 at = {0, 0, 0, 0, 0, 0, 0, 0};
            at[0] = a4[0]; at[1] = a4[1]; at[2] = a4[2]; at[3] = a4[3];
            acc0 = MFMA16(at, bt[0], acc0);
            acc1 = MFMA16(at, bt[1], acc1);
            #pragma unroll
            for (int r = 0; r < 4; ++r) {
                const int row = mt * 16 + quad * 4 + r;
                const float h0 = acc0[r] + bias1[0];
                const float h1 = acc1[r] + bias1[1];
                hT[row * PH + wid * 32 + l15]      = (_Float16)fmaxf(h0, 0.f);
                hT[row * PH + wid * 32 + 16 + l15] = (_Float16)fmaxf(h1, 0.f);
            }
        }
    }
    __syncthreads();   // pT dead from here; oL overlays it

    // ---- GEMM2: o = h @ W2perm + b2perm -> oL[bcol][nn]. M=128,N=144,K=128
    {
        half8 bf2[3][4];
        float bias2[3];
        const int nnt = (wid == 0) ? 3 : 2;
        for (int q = 0; q < nnt; ++q) {
            const int nt = wid + q * 4;
            const _Float16* wr = W2T + (nt * 16 + l15) * 128;
            #pragma unroll
            for (int ks = 0; ks < 4; ++ks) bf2[q][ks] = *(const half8*)(wr + quad * 8 + ks * 32);
            bias2[q] = b2[l15 * 9 + nt];
        }
        for (int mt = 0; mt < 8; ++mt) {
            half8 af[4];
            const _Float16* ar = hT + (mt * 16 + l15) * PH;
            #pragma unroll
            for (int ks = 0; ks < 4; ++ks) af[ks] = *(const half8*)(ar + quad * 8 + ks * 32);
            for (int q = 0; q < nnt; ++q) {
                f32x4 acc = {0.f, 0.f, 0.f, 0.f};
                #pragma unroll
                for (int ks = 0; ks < 4; ++ks) acc = MFMA16(af[ks], bf2[q][ks], acc);
                const int nt = wid + q * 4;
                #pragma unroll
                for (int r = 0; r < 4; ++r)
                    oL[(mt * 16 + quad * 4 + r) * OPITCH + nt * 16 + l15] =
                        (_Float16)(acc[r] + bias2[q]);
            }
        }
    }
    __syncthreads();

    // ---- fold along x, store og3[b][a][i][c][xo] (xo pair per item, b32 store)
    {
        const size_t rowbase = (size_t)(b * 128 + a) * 3;
        #pragma unroll
        for (int it = 0; it < 24; ++it) {
            const int item = tid + it * 256;       // 6144 items = 3i*16c*128m
            const int m  = item & 127;
            const int ic = item >> 7;
            const int i  = ic >> 4, c = ic & 15;
            // xo=2m (xpad odd): j=1 tap from bcol=m
            float ve = (float)oL[m * OPITCH + (i * 3 + 1) * 16 + c];
            // xo=2m+1 (xpad even): j=2 from bcol=m (+ j=0 from bcol=m+1 if valid)
            float vo = (float)oL[m * OPITCH + (i * 3 + 2) * 16 + c];
            if (m < 127) vo += (float)oL[(m + 1) * OPITCH + (i * 3 + 0) * 16 + c];
            half2v pk = {(_Float16)ve, (_Float16)vo};
            *((half2v*)(og3 + ((rowbase + i) * 16 + c) * 256) + m) = pk;
        }
    }
}

// One block per (b,y): coalesced y-fold gather + normalize + mix + softmax.
__global__ __launch_bounds__(256) void gather3_kernel(
    const _Float16* __restrict__ og3, const float* __restrict__ Wc,
    const float* __restrict__ bc, float* __restrict__ out)
{
    __shared__ float sWc[256];
    __shared__ float sbc[16];
    const int tid = threadIdx.x;
    sWc[tid] = Wc[tid];
    if (tid < 16) sbc[tid] = bc[tid];
    __syncthreads();

    const int xo = tid;
    const int y  = blockIdx.x & 255;
    const int b  = blockIdx.x >> 8;
    const int ypad = y + 1;

    float s[CC];
    #pragma unroll
    for (int c = 0; c < CC; ++c) s[c] = 0.f;

    const size_t bb = (size_t)b * 128;
    int ny = 0;
    {
        int aa[2], ii[2];
        if (ypad & 1) { aa[0] = y >> 1; ii[0] = 1; ny = 1; }
        else {
            if (y != 255) { aa[ny] = ypad >> 1; ii[ny] = 0; ++ny; }
            aa[ny] = (ypad >> 1) - 1; ii[ny] = 2; ++ny;
        }
        for (int u = 0; u < ny; ++u) {
            const _Float16* p = og3 + ((bb + aa[u]) * 3 + ii[u]) * 4096 + xo;
            #pragma unroll
            for (int c = 0; c < CC; ++c) s[c] += (float)p[c * 256];
        }
    }
    const int nx = ((xo & 1) == 0) ? 1 : ((xo == 255) ? 1 : 2);
    const float inv = 1.f / ((float)(ny * nx) + 1e-6f);

    float nrm[CC];
    #pragma unroll
    for (int c = 0; c < CC; ++c) nrm[c] = s[c] * inv;

    float lg[CC];
    #pragma unroll
    for (int o = 0; o < CC; ++o) {
        float t = sbc[o];
        #pragma unroll
        for (int c = 0; c < CC; ++c) t = fmaf(sWc[o * CC + c], nrm[c], t);
        lg[o] = t;
    }
    float mx = lg[0];
    #pragma unroll
    for (int o = 1; o < CC; ++o) mx = fmaxf(mx, lg[o]);
    float se = 0.f;
    #pragma unroll
    for (int o = 0; o < CC; ++o) { lg[o] = expf(lg[o] - mx); se += lg[o]; }
    const float isum = 1.f / se;

    const size_t obase = ((size_t)b * CC) * (HH * WW) + (size_t)y * WW + xo;
    #pragma unroll
    for (int c = 0; c < CC; ++c)
        out[obase + (size_t)c * (HH * WW)] = nrm[c] * lg[c] * isum;
}

// ===========================================================================
// FALLBACK (round-2 path, known-good at 456 us) — used only if ws too small.
// ===========================================================================
__global__ __launch_bounds__(256) void prep_kernel(
    const float* __restrict__ W1, const float* __restrict__ W2,
    _Float16* __restrict__ W1T, _Float16* __restrict__ W2T)
{
    const int idx = blockIdx.x * 256 + threadIdx.x;
    if (idx < 128 * K1PAD) {
        const int n = idx / K1PAD;
        const int k = idx - n * K1PAD;
        W1T[idx] = (k < PDIM) ? (_Float16)W1[k * HIDN + n] : (_Float16)0.f;
    }
    if (idx < 144 * 128) {
        const int nn = idx >> 7;
        const int k  = idx & 127;
        const int tap = nn >> 4;
        const int c   = nn & 15;
        W2T[nn * 128 + k] = (_Float16)W2[k * PDIM + c * 9 + tap];
    }
}

__global__ __launch_bounds__(256) void mlp_kernel(
    const float* __restrict__ x,
    const _Float16* __restrict__ W1T, const float* __restrict__ b1,
    const _Float16* __restrict__ W2T, const float* __restrict__ b2,
    _Float16* __restrict__ og)
{
    __shared__ __align__(16) _Float16 pT[128 * PITCH_P];
    __shared__ __align__(16) _Float16 hT[128 * PITCH_H];

    const int tid   = threadIdx.x;
    const int a     = blockIdx.x & 127;
    const int batch = blockIdx.x >> 7;

    const float* xb = x + (size_t)batch * CC * HH * WW;
    for (int idx = tid; idx < 128 * PDIM; idx += 256) {
        const int p    = idx >> 7;
        const int bcol = idx & 127;
        const int c    = p / 9;
        const int rem  = p - c * 9;
        const int i    = rem / 3;
        const int j    = rem - i * 3;
        int ym = 2 * a + i - 1;
        int xm = 2 * bcol + j - 1;
        if (ym < 0) ym = 1;
        if (xm < 0) xm = 1;
        pT[bcol * PITCH_P + p] = (_Float16)xb[(c * HH + ym) * WW + xm];
    }
    for (int idx = tid; idx < 128 * 16; idx += 256) {
        const int bcol = idx >> 4;
        pT[bcol * PITCH_P + PDIM + (idx & 15)] = (_Float16)0.f;
    }
    __syncthreads();

    const int wid  = tid >> 6;
    const int lane = tid & 63;
    const int l15  = lane & 15;
    const int quad = lane >> 4;

    {
        half8 bfr[2][5];
        float bias[2];
        #pragma unroll
        for (int n = 0; n < 2; ++n) {
            const int nt = 2 * wid + n;
            const _Float16* wrow = W1T + (nt * 16 + l15) * K1PAD + quad * 8;
            #pragma unroll
            for (int ks = 0; ks < 5; ++ks) bfr[n][ks] = *(const half8*)(wrow + ks * 32);
            bias[n] = b1[nt * 16 + l15];
        }
        for (int mt = 0; mt < 8; ++mt) {
            f32x4 acc0 = {0.f, 0.f, 0.f, 0.f};
            f32x4 acc1 = {0.f, 0.f, 0.f, 0.f};
            const _Float16* arow = pT + (mt * 16 + l15) * PITCH_P + quad * 8;
            #pragma unroll
            for (int ks = 0; ks < 5; ++ks) {
                const half8 af = *(const half8*)(arow + ks * 32);
                acc0 = MFMA16(af, bfr[0][ks], acc0);
                acc1 = MFMA16(af, bfr[1][ks], acc1);
            }
            #pragma unroll
            for (int r = 0; r < 4; ++r) {
                const int row = mt * 16 + quad * 4 + r;
                float h0 = acc0[r] + bias[0];
                float h1 = acc1[r] + bias[1];
                hT[row * PITCH_H + (2 * wid) * 16 + l15]     = (_Float16)(h0 > 0.f ? h0 : 0.f);
                hT[row * PITCH_H + (2 * wid + 1) * 16 + l15] = (_Float16)(h1 > 0.f ? h1 : 0.f);
            }
        }
    }
    __syncthreads();

    const size_t patch_base = (size_t)batch * 16384 + (size_t)a * 128;
    for (int nt = wid; nt < 9; nt += 4) {
        half8 bfr2[4];
        const _Float16* w2row = W2T + (nt * 16 + l15) * 128 + quad * 8;
        #pragma unroll
        for (int ks = 0; ks < 4; ++ks) bfr2[ks] = *(const half8*)(w2row + ks * 32);
        const float bias2 = b2[l15 * 9 + nt];
        for (int mt = 0; mt < 8; ++mt) {
            f32x4 acc = {0.f, 0.f, 0.f, 0.f};
            const _Float16* arow = hT + (mt * 16 + l15) * PITCH_H + quad * 8;
            #pragma unroll
            for (int ks = 0; ks < 4; ++ks)
                acc = MFMA16(*(const half8*)(arow + ks * 32), bfr2[ks], acc);
            #pragma unroll
            for (int r = 0; r < 4; ++r) {
                const size_t prow = patch_base + mt * 16 + quad * 4 + r;
                og[prow * 144 + nt * 16 + l15] = (_Float16)(acc[r] + bias2);
            }
        }
    }
}

__global__ __launch_bounds__(256) void gather_kernel(
    const _Float16* __restrict__ og, const float* __restrict__ Wc,
    const float* __restrict__ bc, float* __restrict__ out)
{
    __shared__ float sWc[256];
    __shared__ float sbc[16];
    const int tid = threadIdx.x;
    sWc[tid] = Wc[tid];
    if (tid < 16) sbc[tid] = bc[tid];
    __syncthreads();

    const int x     = tid;
    const int y     = blockIdx.x & 255;
    const int batch = blockIdx.x >> 8;

    int alist[2], ilist[2], na = 0;
    if ((y + 1) & 1) { alist[0] = y >> 1; ilist[0] = 1; na = 1; }
    else {
        if (y < 255) { alist[na] = (y + 1) >> 1; ilist[na] = 0; ++na; }
        alist[na] = (y - 1) >> 1; ilist[na] = 2; ++na;
    }
    int blist[2], jlist[2], nb = 0;
    if ((x + 1) & 1) { blist[0] = x >> 1; jlist[0] = 1; nb = 1; }
    else {
        if (x < 255) { blist[nb] = (x + 1) >> 1; jlist[nb] = 0; ++nb; }
        blist[nb] = (x - 1) >> 1; jlist[nb] = 2; ++nb;
    }

    float nrm[CC];
    #pragma unroll
    for (int c = 0; c < CC; ++c) nrm[c] = 0.f;

    const size_t pb = (size_t)batch * 16384;
    for (int u = 0; u < 2; ++u) {
        if (u >= na) break;
        for (int v = 0; v < 2; ++v) {
            if (v >= nb) break;
            const int tap = ilist[u] * 3 + jlist[v];
            const _Float16* orow = og + (pb + (size_t)alist[u] * 128 + blist[v]) * 144 + tap * 16;
            const half8 o0 = *(const half8*)(orow);
            const half8 o1 = *(const half8*)(orow + 8);
            #pragma unroll
            for (int e = 0; e < 8; ++e) { nrm[e] += (float)o0[e]; nrm[8 + e] += (float)o1[e]; }
        }
    }
    const float inv = 1.f / ((float)(na * nb) + 1e-6f);
    #pragma unroll
    for (int c = 0; c < CC; ++c) nrm[c] *= inv;

    float lg[CC];
    #pragma unroll
    for (int o = 0; o < CC; ++o) {
        float t = sbc[o];
        #pragma unroll
        for (int c = 0; c < CC; ++c) t = fmaf(sWc[o * CC + c], nrm[c], t);
        lg[o] = t;
    }
    float mx = lg[0];
    #pragma unroll
    for (int o = 1; o < CC; ++o) mx = fmaxf(mx, lg[o]);
    float se = 0.f;
    #pragma unroll
    for (int o = 0; o < CC; ++o) { lg[o] = expf(lg[o] - mx); se += lg[o]; }
    const float isum = 1.f / se;

    const size_t obase = ((size_t)batch * CC) * (HH * WW) + (size_t)y * WW + x;
    #pragma unroll
    for (int c = 0; c < CC; ++c)
        out[obase + (size_t)c * (HH * WW)] = nrm[c] * lg[c] * isum;
}

// ---------------------------------------------------------------------------
extern "C" void kernel_launch(void* const* d_in, const int* in_sizes, int n_in,
                              void* d_out, int out_size, void* d_ws, size_t ws_size,
                              hipStream_t stream)
{
    const float* x  = (const float*)d_in[0];
    const float* W1 = (const float*)d_in[1];
    const float* b1 = (const float*)d_in[2];
    const float* W2 = (const float*)d_in[3];
    const float* b2 = (const float*)d_in[4];
    const float* Wc = (const float*)d_in[5];
    const float* bc = (const float*)d_in[6];
    float* out = (float*)d_out;

    if (ws_size >= WS_NEEDED3) {
        _Float16* og3 = (_Float16*)d_ws;
        _Float16* xh  = (_Float16*)((char*)d_ws + XH_OFF);
        _Float16* W1T = (_Float16*)((char*)d_ws + W1T3_OFF);
        _Float16* W2T = (_Float16*)((char*)d_ws + W2T3_OFF);

        transpose_kernel<<<dim3(32 * 256), dim3(256), 0, stream>>>(x, xh);
        prep3_kernel<<<dim3(72), dim3(256), 0, stream>>>(W1, W2, W1T, W2T);
        mlp3_kernel<<<dim3(32 * 128), dim3(256), 0, stream>>>(xh, W1T, b1, W2T, b2, og3);
        gather3_kernel<<<dim3(32 * 256), dim3(256), 0, stream>>>(og3, Wc, bc, out);
    } else {
        _Float16* og  = (_Float16*)d_ws;
        _Float16* W1T = (_Float16*)((char*)d_ws + W1T_OFF);
        _Float16* W2T = (_Float16*)((char*)d_ws + W2T_OFF);

        prep_kernel<<<dim3(80), dim3(256), 0, stream>>>(W1, W2, W1T, W2T);
        mlp_kernel<<<dim3(32 * 128), dim3(256), 0, stream>>>(x, W1T, b1, W2T, b2, og);
        gather_kernel<<<dim3(32 * 256), dim3(256), 0, stream>>>(og, Wc, bc, out);
    }
}